// Round 10
// baseline (140.098 us; speedup 1.0000x reference)
//
#include <hip/hip_runtime.h>
#include <stdint.h>

#define B_ROWS 4096
#define D_DIM  512
#define N_TOT  8192
#define TEMP_INV 2.0f   // 1/0.5
#define NB     64       // N_TOT / 128 tiles per dim
#define NTRI   2080     // NB*(NB+1)/2
#define BK     64
#define KT_N   (D_DIM / BK)  // 8 K-steps

typedef __bf16 bf16x8 __attribute__((ext_vector_type(8)));
typedef float  f32x4  __attribute__((ext_vector_type(4)));
typedef unsigned short ushort8 __attribute__((ext_vector_type(8)));

#define VM_WAIT(N) asm volatile("s_waitcnt vmcnt(" #N ")" ::: "memory")
#define LGKM0()    asm volatile("s_waitcnt lgkmcnt(0)" ::: "memory")
#define BAR()      do { asm volatile("" ::: "memory"); \
                        __builtin_amdgcn_s_barrier();  \
                        asm volatile("" ::: "memory"); } while (0)

__device__ __forceinline__ unsigned short f2bf(float f) {
    union { float f; unsigned int u; } c; c.f = f;
    unsigned int u = c.u;
    return (unsigned short)((u + 0x7fffu + ((u >> 16) & 1u)) >> 16);
}

// async global->LDS, 16B per lane. LDS dest is wave-uniform base + lane*16;
// global source is per-lane (carries the swizzle).
__device__ __forceinline__ void gl_lds16(const void* g, void* l) {
    __builtin_amdgcn_global_load_lds(
        (__attribute__((address_space(1))) void*)(uintptr_t)g,
        (__attribute__((address_space(3))) void*)(uintptr_t)l,
        16, 0, 0);
}

// ------- kernel 1: fused L2-normalize (write bf16 z) + positive-pair dot -------
// one wave per pair k; also zeroes rowsum (replaces hipMemsetAsync dispatch)
__global__ __launch_bounds__(256) void normpos_kernel(
    const float* __restrict__ xi, const float* __restrict__ xj,
    unsigned short* __restrict__ z, float* __restrict__ pos,
    float* __restrict__ rowsum) {
    if (blockIdx.x < N_TOT / 256) rowsum[blockIdx.x * 256 + threadIdx.x] = 0.f;
    const int wid  = threadIdx.x >> 6;
    const int lane = threadIdx.x & 63;
    const int k    = blockIdx.x * 4 + wid;
    const float4* a4 = (const float4*)(xi + (size_t)k * D_DIM);
    const float4* b4 = (const float4*)(xj + (size_t)k * D_DIM);
    float4 va0 = a4[2 * lane], va1 = a4[2 * lane + 1];
    float4 vb0 = b4[2 * lane], vb1 = b4[2 * lane + 1];
    float ssa = va0.x*va0.x + va0.y*va0.y + va0.z*va0.z + va0.w*va0.w
              + va1.x*va1.x + va1.y*va1.y + va1.z*va1.z + va1.w*va1.w;
    float ssb = vb0.x*vb0.x + vb0.y*vb0.y + vb0.z*vb0.z + vb0.w*vb0.w
              + vb1.x*vb1.x + vb1.y*vb1.y + vb1.z*vb1.z + vb1.w*vb1.w;
    float dot = va0.x*vb0.x + va0.y*vb0.y + va0.z*vb0.z + va0.w*vb0.w
              + va1.x*vb1.x + va1.y*vb1.y + va1.z*vb1.z + va1.w*vb1.w;
    #pragma unroll
    for (int m = 32; m >= 1; m >>= 1) {
        ssa += __shfl_xor(ssa, m);
        ssb += __shfl_xor(ssb, m);
        dot += __shfl_xor(dot, m);
    }
    const float rna = 1.0f / fmaxf(sqrtf(ssa), 1e-12f);
    const float rnb = 1.0f / fmaxf(sqrtf(ssb), 1e-12f);
    float av[8] = {va0.x, va0.y, va0.z, va0.w, va1.x, va1.y, va1.z, va1.w};
    float bv[8] = {vb0.x, vb0.y, vb0.z, vb0.w, vb1.x, vb1.y, vb1.z, vb1.w};
    union { ushort8 v; unsigned short s[8]; } oa, ob;
    #pragma unroll
    for (int i = 0; i < 8; ++i) {
        oa.s[i] = f2bf(av[i] * rna);
        ob.s[i] = f2bf(bv[i] * rnb);
    }
    *(ushort8*)(z + (size_t)k * D_DIM + lane * 8) = oa.v;
    *(ushort8*)(z + (size_t)(k + B_ROWS) * D_DIM + lane * 8) = ob.v;
    if (lane == 0) pos[k] = dot * rna * rnb;
}

// -------- kernel 2: symmetric fused Gram-row-sum over upper-triangular tiles --------
// v10 = v8's register-lean 8-wave geometry (acc[4][2]=32 AGPR, VGPR~40, 2 blocks/CU)
// + BK=64 (8 iters, 16 barrier rounds -- half of v9's skeleton) + 2-deep counted
// vmcnt. Controlled A/B vs v9: same LDS traffic, same occupancy, half the
// per-iteration barrier/issue skeleton. v7 tested BK=64 before but was confounded
// by an occupancy drop (1.4 blocks/CU); here LDS = 65 KB -> exactly 2 blocks/CU.
// vmcnt audit: stage = exactly 4 VMEM/wave (A x2 rows-halves, B x2; diag stages B
//   redundantly from identical addresses). Top of iter t: outstanding = tile t (4)
//   + tile t+1 (4). VM_WAIT(4) retires tile t. Last iter: only 4 outstanding ->
//   VM_WAIT(0). Stage of tile t+2 reuses buf t%2 only after LGKM0+BAR confirmed
//   all waves' ds_reads of tile t retired.
// Swizzle: v7's verified 8-slot XOR (phys chunk p at row R holds global chunk
//   p ^ ((R>>1)&7)), applied on stage-source and read sides; measured 0 conflicts.
__global__ __launch_bounds__(512, 4) void simrow_kernel(
    const unsigned short* __restrict__ z, float* __restrict__ rowsum) {
    __shared__ unsigned short As[2][128 * BK];  // 2 x 16 KB
    __shared__ unsigned short Bs[2][128 * BK];  // 2 x 16 KB
    __shared__ float rsum[128];
    __shared__ float csum[128];
    const int tid  = threadIdx.x;
    const int lane = tid & 63;
    const int wid  = tid >> 6;   // 0..7

    // map linear block id -> upper-triangular (bi, bj), bi <= bj
    const int t0 = blockIdx.x;
    int bi = (int)(NB + 0.5f - sqrtf((NB + 0.5f) * (NB + 0.5f) - 2.0f * t0));
    if (bi < 0) bi = 0;
    if (bi > NB - 1) bi = NB - 1;
    while (bi > 0 && (bi * NB - bi * (bi - 1) / 2) > t0) --bi;
    while ((bi + 1) * NB - (bi + 1) * bi / 2 <= t0) ++bi;
    const int bj = bi + (t0 - (bi * NB - bi * (bi - 1) / 2));
    const int row0 = bi * 128;
    const int col0 = bj * 128;

    if (tid < 128) { rsum[tid] = 0.f; csum[tid] = 0.f; }
    const bool diag = (bi == bj);

    const int wr = wid >> 2;    // 0..1 : 64-row band
    const int wc = wid & 3;     // 0..3 : 32-col band
    f32x4 acc[4][2] = {};

    // ---- staging: wave wid covers rows [wid*16, wid*16+16) of the 128x64 tile
    // via 2 gl_lds (8 rows x 128B each). lane -> row-in-8 = lane>>3, phys chunk =
    // lane&7. Source chunk for row R: (lane&7) ^ ((R>>1)&7); for g-th 8-row group
    // that is (lane&7) ^ ((g*4 + (lane>>4))&7)  (wid*8 == 0 mod 8).
    const int r8  = lane >> 3;
    const int sc0 = (lane & 7) ^ ((lane >> 4) & 7);
    const int sc1 = sc0 ^ 4;
    const unsigned short* gA0 = z + (size_t)(row0 + wid * 16 + r8)     * D_DIM + sc0 * 8;
    const unsigned short* gA1 = z + (size_t)(row0 + wid * 16 + 8 + r8) * D_DIM + sc1 * 8;
    const unsigned short* gB0 = z + (size_t)(col0 + wid * 16 + r8)     * D_DIM + sc0 * 8;
    const unsigned short* gB1 = z + (size_t)(col0 + wid * 16 + 8 + r8) * D_DIM + sc1 * 8;

    auto stage = [&](int buf, int kt) {
        const int k0 = kt * BK;
        gl_lds16(gA0 + k0, &As[buf][(wid * 16) * BK]);
        gl_lds16(gA1 + k0, &As[buf][(wid * 16 + 8) * BK]);
        gl_lds16(gB0 + k0, &Bs[buf][(wid * 16) * BK]);
        gl_lds16(gB1 + k0, &Bs[buf][(wid * 16 + 8) * BK]);
    };

    // ---- read side: slot for global k-chunk g at row R: (g ^ ((R>>1)&7)) * 8.
    // R = band + mi*16 + ml; band and mi*16 are 0 mod 16 -> (R>>1)&7 = (ml>>1)&7.
    const int kqi = lane >> 4;         // 0..3
    const int ml  = lane & 15;
    const int sw8 = (ml >> 1) & 7;
    const int slot0 = ((0 + kqi) ^ sw8) * 8;   // k-half 0: global chunks 0..3
    const int slot1 = ((4 + kqi) ^ sw8) * 8;   // k-half 1: global chunks 4..7

    auto compute = [&](int buf) {
        bf16x8 af[4], bfr[2];
        // ---- k-half 0 ----
        #pragma unroll
        for (int mi = 0; mi < 4; ++mi)
            af[mi] = *(const bf16x8*)&As[buf][(wr * 64 + mi * 16 + ml) * BK + slot0];
        #pragma unroll
        for (int ni = 0; ni < 2; ++ni)
            bfr[ni] = *(const bf16x8*)&Bs[buf][(wc * 32 + ni * 16 + ml) * BK + slot0];
        #pragma unroll
        for (int mi = 0; mi < 4; ++mi)
            #pragma unroll
            for (int ni = 0; ni < 2; ++ni)
                acc[mi][ni] = __builtin_amdgcn_mfma_f32_16x16x32_bf16(
                    af[mi], bfr[ni], acc[mi][ni], 0, 0, 0);
        // ---- k-half 1 ----
        #pragma unroll
        for (int mi = 0; mi < 4; ++mi)
            af[mi] = *(const bf16x8*)&As[buf][(wr * 64 + mi * 16 + ml) * BK + slot1];
        #pragma unroll
        for (int ni = 0; ni < 2; ++ni)
            bfr[ni] = *(const bf16x8*)&Bs[buf][(wc * 32 + ni * 16 + ml) * BK + slot1];
        #pragma unroll
        for (int mi = 0; mi < 4; ++mi)
            #pragma unroll
            for (int ni = 0; ni < 2; ++ni)
                acc[mi][ni] = __builtin_amdgcn_mfma_f32_16x16x32_bf16(
                    af[mi], bfr[ni], acc[mi][ni], 0, 0, 0);
    };

    // prologue: two tiles in flight
    stage(0, 0);
    stage(1, 1);

    for (int kt = 0; kt < KT_N; ++kt) {
        if (kt < KT_N - 1) { VM_WAIT(4); }   // tile kt landed; kt+1 flying
        else               { VM_WAIT(0); }   // last: drain
        BAR();
        compute(kt & 1);
        LGKM0();             // all ds_reads of buf kt&1 retired
        BAR();
        if (kt + 2 < KT_N) stage(kt & 1, kt + 2);
    }

    // epilogue: e = exp(2*sim), mask diagonal; row sums always, col sums if off-diag
    const int quad = lane >> 4;
    const int cl   = lane & 15;
    float colacc[2] = {0.f, 0.f};
    #pragma unroll
    for (int mi = 0; mi < 4; ++mi) {
        #pragma unroll
        for (int r = 0; r < 4; ++r) {
            const int lrow = wr * 64 + mi * 16 + quad * 4 + r;
            const int irow = row0 + lrow;
            float s = 0.f;
            #pragma unroll
            for (int ni = 0; ni < 2; ++ni) {
                const int jcol = col0 + wc * 32 + ni * 16 + cl;
                float e = __expf(TEMP_INV * acc[mi][ni][r]);
                e = (irow == jcol) ? 0.f : e;
                s += e;
                colacc[ni] += e;
            }
            s += __shfl_xor(s, 1);
            s += __shfl_xor(s, 2);
            s += __shfl_xor(s, 4);
            s += __shfl_xor(s, 8);
            if (cl == 0) atomicAdd(&rsum[lrow], s);
        }
    }
    if (!diag) {
        #pragma unroll
        for (int ni = 0; ni < 2; ++ni) {
            float c = colacc[ni];
            c += __shfl_xor(c, 16);
            c += __shfl_xor(c, 32);
            if (quad == 0) atomicAdd(&csum[wc * 32 + ni * 16 + cl], c);
        }
    }
    __syncthreads();
    if (tid < 128) {
        atomicAdd(&rowsum[row0 + tid], rsum[tid]);
        if (!diag) atomicAdd(&rowsum[col0 + tid], csum[tid]);
    }
}

// ---------------- kernel 3: finalize scalar loss ----------------
__global__ __launch_bounds__(256) void finalize_kernel(
    const float* __restrict__ rowsum, const float* __restrict__ pos,
    float* __restrict__ out) {
    const int t = threadIdx.x;
    float s = 0.f;
    for (int i = t; i < N_TOT; i += 256) s += logf(rowsum[i]);
    float p = 0.f;
    for (int i = t; i < B_ROWS; i += 256) p += pos[i];
    #pragma unroll
    for (int m = 32; m >= 1; m >>= 1) {
        s += __shfl_xor(s, m);
        p += __shfl_xor(p, m);
    }
    __shared__ float ws[4], wp[4];
    if ((t & 63) == 0) { ws[t >> 6] = s; wp[t >> 6] = p; }
    __syncthreads();
    if (t == 0) {
        float tot = ws[0] + ws[1] + ws[2] + ws[3];
        float ptot = wp[0] + wp[1] + wp[2] + wp[3];
        // loss = mean(log denom) - (2*posSum)/(temp*N)
        out[0] = tot / (float)N_TOT - ptot * (2.0f * TEMP_INV / (float)N_TOT);
    }
}

extern "C" void kernel_launch(void* const* d_in, const int* in_sizes, int n_in,
                              void* d_out, int out_size, void* d_ws, size_t ws_size,
                              hipStream_t stream) {
    const float* xi = (const float*)d_in[0];
    const float* xj = (const float*)d_in[1];
    float* out = (float*)d_out;
    char* ws = (char*)d_ws;

    unsigned short* z = (unsigned short*)ws;                       // 8 MB bf16
    float* rowsum = (float*)(ws + (size_t)N_TOT * D_DIM * 2);      // 32 KB
    float* pos = rowsum + N_TOT;                                   // 16 KB

    normpos_kernel<<<B_ROWS / 4, 256, 0, stream>>>(xi, xj, z, pos, rowsum);
    simrow_kernel<<<NTRI, 512, 0, stream>>>(z, rowsum);
    finalize_kernel<<<1, 256, 0, stream>>>(rowsum, pos, out);
}